// Round 2
// baseline (505.965 us; speedup 1.0000x reference)
//
#include <hip/hip_runtime.h>
#include <hip/hip_bf16.h>

#define B_ 128
#define N_ 320
#define C_ 256
#define H_ 8
#define DK 32
#define DV 128
#define HQKV 1536
#define DH 1024
#define MROWS 40960
#define EPS 1e-5f
#define SCALE 0.17677669529663687f

typedef __attribute__((ext_vector_type(4))) float f32x4;
typedef __attribute__((ext_vector_type(8))) short short8_t;
typedef __attribute__((ext_vector_type(4))) short short4_t;

__device__ inline float bf2f(unsigned short u) { return __uint_as_float(((unsigned)u) << 16); }
__device__ inline unsigned short f2bf(float f) {
    unsigned u = __float_as_uint(f);
    u += 0x7FFF + ((u >> 16) & 1);
    return (unsigned short)(u >> 16);
}

// ---- GEMM: C[m,n] = sum_k A[m,k]*B[n,k]; A/B f32 or bf16 per template; bf16 MFMA ----
template <int AF32, int BF32, int STORE_F32>
__global__ __launch_bounds__(256) void gemm_bt(const void* __restrict__ Ap,
                                               const void* __restrict__ Bp,
                                               void* __restrict__ Cout,
                                               int M, int N, int K) {
    __shared__ unsigned short lA[128 * 40];
    __shared__ unsigned short lB[128 * 40];
    const int tid = threadIdx.x;
    const int lane = tid & 63, wid = tid >> 6;
    const int wm = wid >> 1, wn = wid & 1;
    const int lr = lane & 15, lk = (lane >> 4) * 8;
    const int m0 = blockIdx.y * 128, n0 = blockIdx.x * 128;
    f32x4 acc[4][4] = {};
    for (int k0 = 0; k0 < K; k0 += 32) {
        __syncthreads();
#pragma unroll
        for (int j = 0; j < 2; ++j) {
            int idx = j * 256 + tid;
            int row = idx >> 2, cg = idx & 3;
            if (AF32) {
                const float* p = (const float*)Ap + (size_t)(m0 + row) * K + k0 + cg * 8;
                f32x4 a0 = *(const f32x4*)p, a1 = *(const f32x4*)(p + 4);
                short8_t s;
#pragma unroll
                for (int e = 0; e < 4; ++e) { s[e] = (short)f2bf(a0[e]); s[4 + e] = (short)f2bf(a1[e]); }
                *(short8_t*)&lA[row * 40 + cg * 8] = s;
            } else {
                *(short8_t*)&lA[row * 40 + cg * 8] =
                    *(const short8_t*)((const unsigned short*)Ap + (size_t)(m0 + row) * K + k0 + cg * 8);
            }
            if (BF32) {
                const float* p = (const float*)Bp + (size_t)(n0 + row) * K + k0 + cg * 8;
                f32x4 b0 = *(const f32x4*)p, b1 = *(const f32x4*)(p + 4);
                short8_t s;
#pragma unroll
                for (int e = 0; e < 4; ++e) { s[e] = (short)f2bf(b0[e]); s[4 + e] = (short)f2bf(b1[e]); }
                *(short8_t*)&lB[row * 40 + cg * 8] = s;
            } else {
                *(short8_t*)&lB[row * 40 + cg * 8] =
                    *(const short8_t*)((const unsigned short*)Bp + (size_t)(n0 + row) * K + k0 + cg * 8);
            }
        }
        __syncthreads();
        short8_t af[4], bfr[4];
#pragma unroll
        for (int i = 0; i < 4; ++i) af[i] = *(short8_t*)&lA[(wm * 64 + i * 16 + lr) * 40 + lk];
#pragma unroll
        for (int j = 0; j < 4; ++j) bfr[j] = *(short8_t*)&lB[(wn * 64 + j * 16 + lr) * 40 + lk];
#pragma unroll
        for (int i = 0; i < 4; ++i)
#pragma unroll
            for (int j = 0; j < 4; ++j)
                acc[i][j] = __builtin_amdgcn_mfma_f32_16x16x32_bf16(af[i], bfr[j], acc[i][j], 0, 0, 0);
    }
#pragma unroll
    for (int i = 0; i < 4; ++i) {
#pragma unroll
        for (int r = 0; r < 4; ++r) {
            int row = m0 + wm * 64 + i * 16 + (lane >> 4) * 4 + r;
#pragma unroll
            for (int j = 0; j < 4; ++j) {
                int col = n0 + wn * 64 + j * 16 + lr;
                if (STORE_F32)
                    ((float*)Cout)[(size_t)row * N + col] = acc[i][j][r];
                else
                    ((unsigned short*)Cout)[(size_t)row * N + col] = f2bf(acc[i][j][r]);
            }
        }
    }
}

// ---- column stats (sum, sumsq) with atomics ----
template <int ISBF16>
__global__ __launch_bounds__(256) void bn_stats(const void* __restrict__ in, int C, int rowsPerBlock,
                                                float* __restrict__ sum, float* __restrict__ sumsq) {
    __shared__ float ls[2][4][64];
    int c0 = blockIdx.x * 64;
    int r0 = blockIdx.y * rowsPerBlock;
    int col = threadIdx.x & 63, rl = threadIdx.x >> 6;
    int c = c0 + col;
    float s = 0.f, ss = 0.f;
    for (int r = rl; r < rowsPerBlock; r += 4) {
        float v;
        if (ISBF16)
            v = bf2f(((const unsigned short*)in)[(size_t)(r0 + r) * C + c]);
        else
            v = ((const float*)in)[(size_t)(r0 + r) * C + c];
        s += v;
        ss += v * v;
    }
    ls[0][rl][col] = s;
    ls[1][rl][col] = ss;
    __syncthreads();
    if (rl == 0) {
        float t0 = ls[0][0][col] + ls[0][1][col] + ls[0][2][col] + ls[0][3][col];
        float t1 = ls[1][0][col] + ls[1][1][col] + ls[1][2][col] + ls[1][3][col];
        atomicAdd(&sum[c], t0);
        atomicAdd(&sumsq[c], t1);
    }
}

__global__ void bn_finalize(const float* __restrict__ sum, const float* __restrict__ sumsq,
                            const float* __restrict__ g, const float* __restrict__ b,
                            float* __restrict__ scale, float* __restrict__ shift, int C, float invM) {
    int c = blockIdx.x * 256 + threadIdx.x;
    if (c < C) {
        float mean = sum[c] * invM;
        float var = sumsq[c] * invM - mean * mean;
        float sc = g[c] * rsqrtf(var + EPS);
        scale[c] = sc;
        shift[c] = b[c] - mean * sc;
    }
}

__global__ void bias_build(const float* __restrict__ ab, const int* __restrict__ idxs,
                           float* __restrict__ bias, int n_off) {
    int i = blockIdx.x * 256 + threadIdx.x;
    if (i < H_ * N_ * N_) {
        int h = i / (N_ * N_);
        int r = i % (N_ * N_);
        bias[i] = ab[h * n_off + idxs[r]];
    }
}

// ---- fused attention: per (b,h); BN1 applied on load; GELU in epilogue ----
__global__ __launch_bounds__(256) void attn_kernel(const unsigned short* __restrict__ qkv,
                                                   const float* __restrict__ scale1,
                                                   const float* __restrict__ shift1,
                                                   const float* __restrict__ bias,
                                                   unsigned short* __restrict__ attnout) {
    extern __shared__ char smem[];
    unsigned short* Klds = (unsigned short*)smem;   // [320][40]
    unsigned short* Vt = Klds + 320 * 40;           // [128][328] (V transposed)
    unsigned short* Plds = Vt + 128 * 328;          // [64][328]
    float* rowsum = (float*)(Plds + 64 * 328);      // [64]
    const int tid = threadIdx.x;
    const int lane = tid & 63, wid = tid >> 6;
    const int lr = lane & 15, lk = (lane >> 4) * 8;
    const int h = blockIdx.x, b = blockIdx.y;

    for (int idx = tid; idx < 320 * 4; idx += 256) {
        int m = idx >> 2, cg = idx & 3;
        int ck = h * 192 + 32 + cg * 8;
        short8_t raw = *(const short8_t*)&qkv[(size_t)(b * 320 + m) * HQKV + ck];
        short8_t kv;
#pragma unroll
        for (int j = 0; j < 8; ++j)
            kv[j] = (short)f2bf(bf2f((unsigned short)raw[j]) * scale1[ck + j] + shift1[ck + j]);
        *(short8_t*)&Klds[m * 40 + cg * 8] = kv;
    }
    for (int idx = tid; idx < 320 * 16; idx += 256) {
        int m = idx >> 4, dg = idx & 15;
        int cv = h * 192 + 64 + dg * 8;
        short8_t raw = *(const short8_t*)&qkv[(size_t)(b * 320 + m) * HQKV + cv];
#pragma unroll
        for (int j = 0; j < 8; ++j) {
            float f = bf2f((unsigned short)raw[j]) * scale1[cv + j] + shift1[cv + j];
            Vt[(dg * 8 + j) * 328 + m] = f2bf(f);
        }
    }
    __syncthreads();

    for (int qt = 0; qt < 5; ++qt) {
        int q0 = qt * 64;
        int qrow = q0 + wid * 16 + lr;
        int cq = h * 192 + lk;
        short8_t qraw = *(const short8_t*)&qkv[(size_t)(b * 320 + qrow) * HQKV + cq];
        short8_t aq;
#pragma unroll
        for (int j = 0; j < 8; ++j)
            aq[j] = (short)f2bf(bf2f((unsigned short)qraw[j]) * scale1[cq + j] + shift1[cq + j]);

        f32x4 sacc[20] = {};
#pragma unroll
        for (int t = 0; t < 20; ++t) {
            short8_t bk = *(short8_t*)&Klds[(t * 16 + lr) * 40 + lk];
            sacc[t] = __builtin_amdgcn_mfma_f32_16x16x32_bf16(aq, bk, sacc[t], 0, 0, 0);
        }
        const int rbase = q0 + wid * 16 + (lane >> 4) * 4;
        float mrow[4] = {-1e30f, -1e30f, -1e30f, -1e30f};
#pragma unroll
        for (int t = 0; t < 20; ++t) {
#pragma unroll
            for (int r = 0; r < 4; ++r) {
                float sv = sacc[t][r] * SCALE + bias[((size_t)h * 320 + rbase + r) * 320 + t * 16 + lr];
                sacc[t][r] = sv;
                mrow[r] = fmaxf(mrow[r], sv);
            }
        }
#pragma unroll
        for (int r = 0; r < 4; ++r) {
#pragma unroll
            for (int ms = 1; ms < 16; ms <<= 1) mrow[r] = fmaxf(mrow[r], __shfl_xor(mrow[r], ms));
        }
        float sumr[4] = {0.f, 0.f, 0.f, 0.f};
#pragma unroll
        for (int t = 0; t < 20; ++t) {
#pragma unroll
            for (int r = 0; r < 4; ++r) {
                float p = __expf(sacc[t][r] - mrow[r]);
                sumr[r] += p;
                Plds[(wid * 16 + (lane >> 4) * 4 + r) * 328 + t * 16 + lr] = f2bf(p);
            }
        }
#pragma unroll
        for (int r = 0; r < 4; ++r) {
#pragma unroll
            for (int ms = 1; ms < 16; ms <<= 1) sumr[r] += __shfl_xor(sumr[r], ms);
            if (lr == 0) rowsum[wid * 16 + (lane >> 4) * 4 + r] = sumr[r];
        }
        __syncthreads();

        f32x4 oacc[8] = {};
#pragma unroll
        for (int ks = 0; ks < 10; ++ks) {
            short8_t ap = *(short8_t*)&Plds[(wid * 16 + lr) * 328 + ks * 32 + lk];
#pragma unroll
            for (int dt = 0; dt < 8; ++dt) {
                short8_t bv = *(short8_t*)&Vt[(dt * 16 + lr) * 328 + ks * 32 + lk];
                oacc[dt] = __builtin_amdgcn_mfma_f32_16x16x32_bf16(ap, bv, oacc[dt], 0, 0, 0);
            }
        }
#pragma unroll
        for (int r = 0; r < 4; ++r) {
            float inv = 1.0f / rowsum[wid * 16 + (lane >> 4) * 4 + r];
            int nrow = b * 320 + rbase + r;
#pragma unroll
            for (int dt = 0; dt < 8; ++dt) {
                float v = oacc[dt][r] * inv;
                float ge = 0.5f * v * (1.0f + erff(v * 0.70710678118f));
                attnout[(size_t)nrow * DH + h * 128 + dt * 16 + lr] = f2bf(ge);
            }
        }
        __syncthreads();
    }
}

__global__ void bn_apply(const float* __restrict__ proj, const float* __restrict__ scale,
                         const float* __restrict__ shift, float* __restrict__ out) {
    int i = blockIdx.x * 256 + threadIdx.x;
    const int total = MROWS * C_ / 4;
    for (; i < total; i += gridDim.x * 256) {
        f32x4 v = *(const f32x4*)&proj[(size_t)i * 4];
        int c = (i * 4) & 255;
        f32x4 o;
#pragma unroll
        for (int j = 0; j < 4; ++j) o[j] = v[j] * scale[c + j] + shift[c + j];
        *(f32x4*)&out[(size_t)i * 4] = o;
    }
}

extern "C" void kernel_launch(void* const* d_in, const int* in_sizes, int n_in,
                              void* d_out, int out_size, void* d_ws, size_t ws_size,
                              hipStream_t stream) {
    const float* x = (const float*)d_in[0];
    const float* Wqkv = (const float*)d_in[1];
    const float* g1 = (const float*)d_in[2];
    const float* b1 = (const float*)d_in[3];
    const float* ab = (const float*)d_in[4];
    const float* Wproj = (const float*)d_in[5];
    const float* g2 = (const float*)d_in[6];
    const float* b2 = (const float*)d_in[7];
    const int* idxs = (const int*)d_in[8];
    const int n_off = in_sizes[4] / H_;

    char* ws = (char*)d_ws;
    unsigned short* qkv = (unsigned short*)ws;                    // 40960*1536 bf16
    unsigned short* attnout = (unsigned short*)(ws + 125829120);  // 40960*1024 bf16
    float* proj = (float*)(ws + 209715200);                       // 40960*256 f32
    float* bias = (float*)(ws + 251658240);                       // 8*320*320 f32
    float* stats = (float*)(ws + 254935040);
    float* sum1 = stats;
    float* sumsq1 = stats + 1536;
    float* sum2 = stats + 3072;
    float* sumsq2 = sum2 + 256;
    float* scale1 = sumsq2 + 256;
    float* shift1 = scale1 + 1536;
    float* scale2 = shift1 + 1536;
    float* shift2 = scale2 + 256;

    hipMemsetAsync(stats, 0, 3584 * 4, stream);
    bias_build<<<dim3((H_ * N_ * N_ + 255) / 256), 256, 0, stream>>>(ab, idxs, bias, n_off);
    gemm_bt<1, 1, 0><<<dim3(12, 320), 256, 0, stream>>>(x, Wqkv, qkv, MROWS, HQKV, C_);
    bn_stats<1><<<dim3(24, 32), 256, 0, stream>>>(qkv, HQKV, 1280, sum1, sumsq1);
    bn_finalize<<<dim3(6), 256, 0, stream>>>(sum1, sumsq1, g1, b1, scale1, shift1, HQKV, 1.0f / MROWS);
    hipFuncSetAttribute((const void*)attn_kernel, hipFuncAttributeMaxDynamicSharedMemorySize, 151808);
    attn_kernel<<<dim3(8, 128), 256, 151808, stream>>>(qkv, scale1, shift1, bias, attnout);
    gemm_bt<0, 1, 1><<<dim3(2, 320), 256, 0, stream>>>(attnout, Wproj, proj, MROWS, C_, DH);
    bn_stats<0><<<dim3(4, 64), 256, 0, stream>>>(proj, C_, 640, sum2, sumsq2);
    bn_finalize<<<dim3(1), 256, 0, stream>>>(sum2, sumsq2, g2, b2, scale2, shift2, C_, 1.0f / MROWS);
    bn_apply<<<dim3(2048), 256, 0, stream>>>(proj, scale2, shift2, (float*)d_out);
}

// Round 4
// 496.507 us; speedup vs baseline: 1.0190x; 1.0190x over previous
//
#include <hip/hip_runtime.h>
#include <hip/hip_bf16.h>

#define B_ 128
#define N_ 320
#define C_ 256
#define H_ 8
#define HQKV 1536
#define DH 1024
#define MROWS 40960
#define EPS 1e-5f
#define SCALE 0.17677669529663687f

typedef __attribute__((ext_vector_type(4))) float f32x4;
typedef __attribute__((ext_vector_type(8))) short short8_t;
typedef __attribute__((ext_vector_type(4))) short short4_t;

__device__ inline float bf2f(unsigned short u) { return __uint_as_float(((unsigned)u) << 16); }
__device__ inline unsigned short f2bf(float f) {
    unsigned u = __float_as_uint(f);
    u += 0x7FFF + ((u >> 16) & 1);
    return (unsigned short)(u >> 16);
}

__global__ void conv_bf16(const float* __restrict__ in, unsigned short* __restrict__ out, int n4) {
    int i = blockIdx.x * 256 + threadIdx.x;
    if (i < n4) {
        f32x4 v = ((const f32x4*)in)[i];
        short4_t o;
#pragma unroll
        for (int j = 0; j < 4; ++j) o[j] = (short)f2bf(v[j]);
        ((short4_t*)out)[i] = o;
    }
}

// ---- GEMM1: qkv = x @ Wqkv^T; routes q/k -> qkB[bh][n][64], v -> vT[bh][d][320]; fused BN stats ----
__global__ __launch_bounds__(256) void gemm_qkv(const unsigned short* __restrict__ A,
                                                const unsigned short* __restrict__ Bm,
                                                unsigned short* __restrict__ qkB,
                                                unsigned short* __restrict__ vT,
                                                float* __restrict__ sum1, float* __restrict__ sumsq1) {
    __shared__ unsigned short lA[128 * 40];
    __shared__ unsigned short lB[128 * 40];
    const int tid = threadIdx.x;
    const int lane = tid & 63, wid = tid >> 6;
    const int wm = wid >> 1, wn = wid & 1;
    const int lr = lane & 15, g = lane >> 4, lk = g * 8;
    const int m0 = blockIdx.y * 128, n0 = blockIdx.x * 128;
    f32x4 acc[4][4] = {};
    for (int k0 = 0; k0 < 256; k0 += 32) {
        __syncthreads();
#pragma unroll
        for (int j = 0; j < 2; ++j) {
            int idx = j * 256 + tid;
            int row = idx >> 2, cg = idx & 3;
            *(short8_t*)&lA[row * 40 + cg * 8] = *(const short8_t*)&A[(size_t)(m0 + row) * 256 + k0 + cg * 8];
            *(short8_t*)&lB[row * 40 + cg * 8] = *(const short8_t*)&Bm[(size_t)(n0 + row) * 256 + k0 + cg * 8];
        }
        __syncthreads();
        short8_t af[4], bfr[4];
#pragma unroll
        for (int i = 0; i < 4; ++i) af[i] = *(short8_t*)&lA[(wm * 64 + i * 16 + lr) * 40 + lk];
#pragma unroll
        for (int j = 0; j < 4; ++j) bfr[j] = *(short8_t*)&lB[(wn * 64 + j * 16 + lr) * 40 + lk];
#pragma unroll
        for (int i = 0; i < 4; ++i)
#pragma unroll
            for (int j = 0; j < 4; ++j)
                acc[i][j] = __builtin_amdgcn_mfma_f32_16x16x32_bf16(af[i], bfr[j], acc[i][j], 0, 0, 0);
    }
    // epilogue: route + per-column partial stats
    float cs[4] = {0.f, 0.f, 0.f, 0.f}, css[4] = {0.f, 0.f, 0.f, 0.f};
#pragma unroll
    for (int i = 0; i < 4; ++i) {
#pragma unroll
        for (int r = 0; r < 4; ++r) {
            int row = m0 + wm * 64 + i * 16 + g * 4 + r;
            int bq = row / 320;
            int n = row - bq * 320;
#pragma unroll
            for (int j = 0; j < 4; ++j) {
                float val = acc[i][j][r];
                cs[j] += val;
                css[j] += val * val;
                int col = n0 + wn * 64 + j * 16 + lr;
                int hh = col / 192;
                int cm = col - hh * 192;
                if (cm < 64)
                    qkB[((size_t)(bq * 8 + hh) * 320 + n) * 64 + cm] = f2bf(val);
                else
                    vT[((size_t)(bq * 8 + hh) * 128 + (cm - 64)) * 320 + n] = f2bf(val);
            }
        }
    }
    __syncthreads();
    float* red_s = (float*)lA;        // [8][128]
    float* red_ss = (float*)lA + 1024;  // [8][128]
#pragma unroll
    for (int j = 0; j < 4; ++j) {
        int c = wn * 64 + j * 16 + lr;
        red_s[(wm * 4 + g) * 128 + c] = cs[j];
        red_ss[(wm * 4 + g) * 128 + c] = css[j];
    }
    __syncthreads();
    if (tid < 128) {
        float s = 0.f;
#pragma unroll
        for (int u = 0; u < 8; ++u) s += red_s[u * 128 + tid];
        atomicAdd(&sum1[n0 + tid], s);
    } else {
        int c = tid - 128;
        float s = 0.f;
#pragma unroll
        for (int u = 0; u < 8; ++u) s += red_ss[u * 128 + c];
        atomicAdd(&sumsq1[n0 + c], s);
    }
}

// ---- GEMM2: d_out = attnout @ Wproj^T (f32) + fused stats ----
__global__ __launch_bounds__(256) void gemm_proj(const unsigned short* __restrict__ A,
                                                 const unsigned short* __restrict__ Bm,
                                                 float* __restrict__ Cout,
                                                 float* __restrict__ sum2, float* __restrict__ sumsq2) {
    __shared__ unsigned short lA[128 * 40];
    __shared__ unsigned short lB[128 * 40];
    const int tid = threadIdx.x;
    const int lane = tid & 63, wid = tid >> 6;
    const int wm = wid >> 1, wn = wid & 1;
    const int lr = lane & 15, g = lane >> 4, lk = g * 8;
    const int m0 = blockIdx.y * 128, n0 = blockIdx.x * 128;
    f32x4 acc[4][4] = {};
    for (int k0 = 0; k0 < 1024; k0 += 32) {
        __syncthreads();
#pragma unroll
        for (int j = 0; j < 2; ++j) {
            int idx = j * 256 + tid;
            int row = idx >> 2, cg = idx & 3;
            *(short8_t*)&lA[row * 40 + cg * 8] = *(const short8_t*)&A[(size_t)(m0 + row) * 1024 + k0 + cg * 8];
            *(short8_t*)&lB[row * 40 + cg * 8] = *(const short8_t*)&Bm[(size_t)(n0 + row) * 1024 + k0 + cg * 8];
        }
        __syncthreads();
        short8_t af[4], bfr[4];
#pragma unroll
        for (int i = 0; i < 4; ++i) af[i] = *(short8_t*)&lA[(wm * 64 + i * 16 + lr) * 40 + lk];
#pragma unroll
        for (int j = 0; j < 4; ++j) bfr[j] = *(short8_t*)&lB[(wn * 64 + j * 16 + lr) * 40 + lk];
#pragma unroll
        for (int i = 0; i < 4; ++i)
#pragma unroll
            for (int j = 0; j < 4; ++j)
                acc[i][j] = __builtin_amdgcn_mfma_f32_16x16x32_bf16(af[i], bfr[j], acc[i][j], 0, 0, 0);
    }
    float cs[4] = {0.f, 0.f, 0.f, 0.f}, css[4] = {0.f, 0.f, 0.f, 0.f};
#pragma unroll
    for (int i = 0; i < 4; ++i) {
#pragma unroll
        for (int r = 0; r < 4; ++r) {
            int row = m0 + wm * 64 + i * 16 + g * 4 + r;
#pragma unroll
            for (int j = 0; j < 4; ++j) {
                float val = acc[i][j][r];
                cs[j] += val;
                css[j] += val * val;
                int col = n0 + wn * 64 + j * 16 + lr;
                Cout[(size_t)row * 256 + col] = val;
            }
        }
    }
    __syncthreads();
    float* red_s = (float*)lA;
    float* red_ss = (float*)lA + 1024;
#pragma unroll
    for (int j = 0; j < 4; ++j) {
        int c = wn * 64 + j * 16 + lr;
        red_s[(wm * 4 + g) * 128 + c] = cs[j];
        red_ss[(wm * 4 + g) * 128 + c] = css[j];
    }
    __syncthreads();
    if (tid < 128) {
        float s = 0.f;
#pragma unroll
        for (int u = 0; u < 8; ++u) s += red_s[u * 128 + tid];
        atomicAdd(&sum2[n0 + tid], s);
    } else {
        int c = tid - 128;
        float s = 0.f;
#pragma unroll
        for (int u = 0; u < 8; ++u) s += red_ss[u * 128 + c];
        atomicAdd(&sumsq2[n0 + c], s);
    }
}

__global__ void bn_finalize(const float* __restrict__ sum, const float* __restrict__ sumsq,
                            const float* __restrict__ g, const float* __restrict__ b,
                            float* __restrict__ scale, float* __restrict__ shift, int C, float invM) {
    int c = blockIdx.x * 256 + threadIdx.x;
    if (c < C) {
        float mean = sum[c] * invM;
        float var = sumsq[c] * invM - mean * mean;
        float sc = g[c] * rsqrtf(var + EPS);
        scale[c] = sc;
        shift[c] = b[c] - mean * sc;
    }
}

// wq[h*32+c] = sq*sk*SCALE (applied to Q); w2[h*32+c] = tq*sk*SCALE (for uk)
__global__ void prep_w(const float* __restrict__ scale1, const float* __restrict__ shift1,
                       float* __restrict__ wq, float* __restrict__ w2) {
    int c = threadIdx.x;
    if (c < 256) {
        int h = c >> 5, cc = c & 31;
        int qch = h * 192 + cc, kch = qch + 32;
        wq[c] = scale1[qch] * scale1[kch] * SCALE;
        w2[c] = shift1[qch] * scale1[kch] * SCALE;
    }
}

// uk[bh*320+m] = sum_c w2[h,c] * k_raw[bh,m,c]
__global__ void uk_kernel(const unsigned short* __restrict__ qkB, const float* __restrict__ w2,
                          float* __restrict__ uk) {
    int idx = blockIdx.x * 256 + threadIdx.x;
    if (idx < 128 * 8 * 320) {
        int bh = idx / 320;
        int h = bh & 7;
        const unsigned short* kp = &qkB[(size_t)idx * 64 + 32];
        float s = 0.f;
#pragma unroll
        for (int c4 = 0; c4 < 4; ++c4) {
            short8_t kk = *(const short8_t*)&kp[c4 * 8];
#pragma unroll
            for (int j = 0; j < 8; ++j) s += bf2f((unsigned short)kk[j]) * w2[(h << 5) + c4 * 8 + j];
        }
        uk[idx] = s;
    }
}

__global__ void bias_build(const float* __restrict__ ab, const int* __restrict__ idxs,
                           float* __restrict__ bias, int n_off) {
    int i = blockIdx.x * 256 + threadIdx.x;
    if (i < H_ * N_ * N_) {
        int h = i / (N_ * N_);
        int r = i % (N_ * N_);
        bias[i] = ab[h * n_off + idxs[r]];
    }
}

// ---- attention: block=(h, b*5+qt), 4 waves, each wave 16 q-rows; K/V direct from global ----
__global__ __launch_bounds__(256) void attn_kernel(const unsigned short* __restrict__ qkB,
                                                   const unsigned short* __restrict__ vT,
                                                   const float* __restrict__ wq,
                                                   const float* __restrict__ uk,
                                                   const float* __restrict__ bias,
                                                   const float* __restrict__ scale1,
                                                   const float* __restrict__ shift1,
                                                   unsigned short* __restrict__ attnout) {
    __shared__ unsigned short Plds[4][16 * 40];
    const int tid = threadIdx.x;
    const int lane = tid & 63, wid = tid >> 6;
    const int lr = lane & 15, g = lane >> 4;
    const int h = blockIdx.x;
    const int b = blockIdx.y / 5, qt = blockIdx.y % 5;
    const int bh = b * 8 + h;

    // Q fragment (scaled by wq)
    int qrow = qt * 64 + wid * 16 + lr;
    short8_t qraw = *(const short8_t*)&qkB[((size_t)bh * 320 + qrow) * 64 + g * 8];
    short8_t aq;
#pragma unroll
    for (int j = 0; j < 8; ++j)
        aq[j] = (short)f2bf(bf2f((unsigned short)qraw[j]) * wq[(h << 5) + g * 8 + j]);

    f32x4 oacc[8] = {};
    float sumr[4] = {0.f, 0.f, 0.f, 0.f};
    unsigned short* Pw = Plds[wid];
    const unsigned short* Kbase = &qkB[(size_t)bh * 320 * 64 + 32 + g * 8];
    const unsigned short* Vbase = &vT[(size_t)bh * 128 * 320 + g * 8];
    const float* biasrow = &bias[(size_t)h * 320 * 320];
    const float* ukrow = &uk[(size_t)bh * 320];
    const int nloc0 = qt * 64 + wid * 16 + g * 4;

    for (int kv = 0; kv < 10; ++kv) {
        short8_t bk0 = *(const short8_t*)&Kbase[(size_t)(kv * 32 + lr) * 64];
        short8_t bk1 = *(const short8_t*)&Kbase[(size_t)(kv * 32 + 16 + lr) * 64];
        f32x4 z = {};
        f32x4 sacc0 = __builtin_amdgcn_mfma_f32_16x16x32_bf16(aq, bk0, z, 0, 0, 0);
        f32x4 sacc1 = __builtin_amdgcn_mfma_f32_16x16x32_bf16(aq, bk1, z, 0, 0, 0);
        int col0 = kv * 32 + lr;
        float uk0 = ukrow[col0], uk1 = ukrow[col0 + 16];
#pragma unroll
        for (int r = 0; r < 4; ++r) {
            int nloc = nloc0 + r;
            float s0 = sacc0[r] + uk0 + biasrow[(size_t)nloc * 320 + col0];
            float s1 = sacc1[r] + uk1 + biasrow[(size_t)nloc * 320 + col0 + 16];
            float p0 = __expf(s0), p1 = __expf(s1);
            sumr[r] += p0 + p1;
            Pw[(g * 4 + r) * 40 + lr] = f2bf(p0);
            Pw[(g * 4 + r) * 40 + 16 + lr] = f2bf(p1);
        }
        short8_t ap = *(short8_t*)&Pw[lr * 40 + g * 8];
#pragma unroll
        for (int dt = 0; dt < 8; ++dt) {
            short8_t bv = *(const short8_t*)&Vbase[(size_t)(dt * 16 + lr) * 320 + kv * 32];
            oacc[dt] = __builtin_amdgcn_mfma_f32_16x16x32_bf16(ap, bv, oacc[dt], 0, 0, 0);
        }
    }
    // epilogue: normalize, fold V-BN, GELU
#pragma unroll
    for (int r = 0; r < 4; ++r)
#pragma unroll
        for (int ms = 1; ms < 16; ms <<= 1) sumr[r] += __shfl_xor(sumr[r], ms);
    float svv[8], tvv[8];
#pragma unroll
    for (int dt = 0; dt < 8; ++dt) {
        int ch = h * 192 + 64 + dt * 16 + lr;
        svv[dt] = scale1[ch];
        tvv[dt] = shift1[ch];
    }
#pragma unroll
    for (int r = 0; r < 4; ++r) {
        float inv = 1.0f / sumr[r];
        size_t nrow = (size_t)b * 320 + nloc0 + r;
#pragma unroll
        for (int dt = 0; dt < 8; ++dt) {
            float v = oacc[dt][r] * inv * svv[dt] + tvv[dt];
            float ge = 0.5f * v * (1.0f + erff(v * 0.70710678118f));
            attnout[nrow * 1024 + h * 128 + dt * 16 + lr] = f2bf(ge);
        }
    }
}

__global__ void bn_apply(float* __restrict__ out, const float* __restrict__ scale,
                         const float* __restrict__ shift) {
    int i = blockIdx.x * 256 + threadIdx.x;
    const int total = MROWS * C_ / 4;
    for (; i < total; i += gridDim.x * 256) {
        f32x4 v = *(const f32x4*)&out[(size_t)i * 4];
        int c = (i * 4) & 255;
        f32x4 o;
#pragma unroll
        for (int j = 0; j < 4; ++j) o[j] = v[j] * scale[c + j] + shift[c + j];
        *(f32x4*)&out[(size_t)i * 4] = o;
    }
}

extern "C" void kernel_launch(void* const* d_in, const int* in_sizes, int n_in,
                              void* d_out, int out_size, void* d_ws, size_t ws_size,
                              hipStream_t stream) {
    const float* x = (const float*)d_in[0];
    const float* Wqkv = (const float*)d_in[1];
    const float* g1 = (const float*)d_in[2];
    const float* b1 = (const float*)d_in[3];
    const float* ab = (const float*)d_in[4];
    const float* Wproj = (const float*)d_in[5];
    const float* g2 = (const float*)d_in[6];
    const float* b2 = (const float*)d_in[7];
    const int* idxs = (const int*)d_in[8];
    const int n_off = in_sizes[4] / H_;

    char* ws = (char*)d_ws;
    unsigned short* qkB = (unsigned short*)ws;                       // 128*8*320*64 bf16 = 41.9MB
    unsigned short* vT = (unsigned short*)(ws + 41943040);           // 128*8*128*320 bf16 = 83.9MB
    unsigned short* attnout = (unsigned short*)(ws + 125829120);     // 40960*1024 bf16 = 83.9MB
    unsigned short* xb = attnout;                                    // overlap: dead before attn
    float* bias = (float*)(ws + 209715200);                          // 3.28MB
    float* uk = (float*)(ws + 212992000);                            // 1.31MB
    unsigned short* wqb = (unsigned short*)(ws + 214302720);         // 1536*256 bf16
    unsigned short* wpb = (unsigned short*)(ws + 215089152);         // 256*1024 bf16
    float* stats = (float*)(ws + 215613440);
    float* sum1 = stats;
    float* sumsq1 = stats + 1536;
    float* sum2 = stats + 3072;
    float* sumsq2 = sum2 + 256;
    float* scale1 = sumsq2 + 256;
    float* shift1 = scale1 + 1536;
    float* scale2 = shift1 + 1536;
    float* shift2 = scale2 + 256;
    float* wq = shift2 + 256;
    float* w2 = wq + 256;

    hipMemsetAsync(stats, 0, 3584 * 4, stream);
    conv_bf16<<<dim3(10240), 256, 0, stream>>>(x, xb, 2621440);
    conv_bf16<<<dim3(384), 256, 0, stream>>>(Wqkv, wqb, 98304);
    conv_bf16<<<dim3(256), 256, 0, stream>>>(Wproj, wpb, 65536);
    bias_build<<<dim3(3200), 256, 0, stream>>>(ab, idxs, bias, n_off);
    gemm_qkv<<<dim3(12, 320), 256, 0, stream>>>(xb, wqb, qkB, vT, sum1, sumsq1);
    bn_finalize<<<dim3(6), 256, 0, stream>>>(sum1, sumsq1, g1, b1, scale1, shift1, 1536, 1.0f / MROWS);
    prep_w<<<dim3(1), 256, 0, stream>>>(scale1, shift1, wq, w2);
    uk_kernel<<<dim3(1280), 256, 0, stream>>>(qkB, w2, uk);
    attn_kernel<<<dim3(8, 640), 256, 0, stream>>>(qkB, vT, wq, uk, bias, scale1, shift1, attnout);
    gemm_proj<<<dim3(2, 320), 256, 0, stream>>>(attnout, wpb, (float*)d_out, sum2, sumsq2);
    bn_finalize<<<dim3(1), 256, 0, stream>>>(sum2, sumsq2, g2, b2, scale2, shift2, 256, 1.0f / MROWS);
    bn_apply<<<dim3(2048), 256, 0, stream>>>((float*)d_out, scale2, shift2);
}

// Round 5
// 364.388 us; speedup vs baseline: 1.3885x; 1.3626x over previous
//
#include <hip/hip_runtime.h>
#include <hip/hip_bf16.h>

#define B_ 128
#define N_ 320
#define C_ 256
#define H_ 8
#define HQKV 1536
#define DH 1024
#define MROWS 40960
#define EPS 1e-5f
#define SCALE 0.17677669529663687f

typedef __attribute__((ext_vector_type(4))) float f32x4;
typedef __attribute__((ext_vector_type(8))) short short8_t;
typedef __attribute__((ext_vector_type(4))) short short4_t;

__device__ inline float bf2f(unsigned short u) { return __uint_as_float(((unsigned)u) << 16); }
__device__ inline unsigned short f2bf(float f) {
    unsigned u = __float_as_uint(f);
    u += 0x7FFF + ((u >> 16) & 1);
    return (unsigned short)(u >> 16);
}

__global__ void conv_bf16(const float* __restrict__ in, unsigned short* __restrict__ out, int n4) {
    int i = blockIdx.x * 256 + threadIdx.x;
    if (i < n4) {
        f32x4 v = ((const f32x4*)in)[i];
        short4_t o;
#pragma unroll
        for (int j = 0; j < 4; ++j) o[j] = (short)f2bf(v[j]);
        ((short4_t*)out)[i] = o;
    }
}

// ---- GEMM1: qkv = x @ Wqkv^T; routes q/k -> qkB[bh][n][64], v -> vT[bh][d][320]; fused BN stats ----
__global__ __launch_bounds__(256) void gemm_qkv(const unsigned short* __restrict__ A,
                                                const unsigned short* __restrict__ Bm,
                                                unsigned short* __restrict__ qkB,
                                                unsigned short* __restrict__ vT,
                                                float* __restrict__ sum1, float* __restrict__ sumsq1) {
    __shared__ unsigned short lA[128 * 40];
    __shared__ unsigned short lB[128 * 40];
    const int tid = threadIdx.x;
    const int lane = tid & 63, wid = tid >> 6;
    const int wm = wid >> 1, wn = wid & 1;
    const int lr = lane & 15, g = lane >> 4, lk = g * 8;
    const int m0 = blockIdx.y * 128, n0 = blockIdx.x * 128;
    f32x4 acc[4][4] = {};
    for (int k0 = 0; k0 < 256; k0 += 32) {
        __syncthreads();
#pragma unroll
        for (int j = 0; j < 2; ++j) {
            int idx = j * 256 + tid;
            int row = idx >> 2, cg = idx & 3;
            *(short8_t*)&lA[row * 40 + cg * 8] = *(const short8_t*)&A[(size_t)(m0 + row) * 256 + k0 + cg * 8];
            *(short8_t*)&lB[row * 40 + cg * 8] = *(const short8_t*)&Bm[(size_t)(n0 + row) * 256 + k0 + cg * 8];
        }
        __syncthreads();
        short8_t af[4], bfr[4];
#pragma unroll
        for (int i = 0; i < 4; ++i) af[i] = *(short8_t*)&lA[(wm * 64 + i * 16 + lr) * 40 + lk];
#pragma unroll
        for (int j = 0; j < 4; ++j) bfr[j] = *(short8_t*)&lB[(wn * 64 + j * 16 + lr) * 40 + lk];
#pragma unroll
        for (int i = 0; i < 4; ++i)
#pragma unroll
            for (int j = 0; j < 4; ++j)
                acc[i][j] = __builtin_amdgcn_mfma_f32_16x16x32_bf16(af[i], bfr[j], acc[i][j], 0, 0, 0);
    }
    float cs[4] = {0.f, 0.f, 0.f, 0.f}, css[4] = {0.f, 0.f, 0.f, 0.f};
#pragma unroll
    for (int i = 0; i < 4; ++i) {
#pragma unroll
        for (int r = 0; r < 4; ++r) {
            int row = m0 + wm * 64 + i * 16 + g * 4 + r;
            int bq = row / 320;
            int n = row - bq * 320;
#pragma unroll
            for (int j = 0; j < 4; ++j) {
                float val = acc[i][j][r];
                cs[j] += val;
                css[j] += val * val;
                int col = n0 + wn * 64 + j * 16 + lr;
                int hh = col / 192;
                int cm = col - hh * 192;
                if (cm < 64)
                    qkB[((size_t)(bq * 8 + hh) * 320 + n) * 64 + cm] = f2bf(val);
                else
                    vT[((size_t)(bq * 8 + hh) * 128 + (cm - 64)) * 320 + n] = f2bf(val);
            }
        }
    }
    __syncthreads();
    float* red_s = (float*)lA;
    float* red_ss = (float*)lA + 1024;
#pragma unroll
    for (int j = 0; j < 4; ++j) {
        int c = wn * 64 + j * 16 + lr;
        red_s[(wm * 4 + g) * 128 + c] = cs[j];
        red_ss[(wm * 4 + g) * 128 + c] = css[j];
    }
    __syncthreads();
    if (tid < 128) {
        float s = 0.f;
#pragma unroll
        for (int u = 0; u < 8; ++u) s += red_s[u * 128 + tid];
        atomicAdd(&sum1[n0 + tid], s);
    } else {
        int c = tid - 128;
        float s = 0.f;
#pragma unroll
        for (int u = 0; u < 8; ++u) s += red_ss[u * 128 + c];
        atomicAdd(&sumsq1[n0 + c], s);
    }
}

// ---- GEMM2: d_out = attnout @ Wproj^T (f32) + fused stats ----
__global__ __launch_bounds__(256) void gemm_proj(const unsigned short* __restrict__ A,
                                                 const unsigned short* __restrict__ Bm,
                                                 float* __restrict__ Cout,
                                                 float* __restrict__ sum2, float* __restrict__ sumsq2) {
    __shared__ unsigned short lA[128 * 40];
    __shared__ unsigned short lB[128 * 40];
    const int tid = threadIdx.x;
    const int lane = tid & 63, wid = tid >> 6;
    const int wm = wid >> 1, wn = wid & 1;
    const int lr = lane & 15, g = lane >> 4, lk = g * 8;
    const int m0 = blockIdx.y * 128, n0 = blockIdx.x * 128;
    f32x4 acc[4][4] = {};
    for (int k0 = 0; k0 < 1024; k0 += 32) {
        __syncthreads();
#pragma unroll
        for (int j = 0; j < 2; ++j) {
            int idx = j * 256 + tid;
            int row = idx >> 2, cg = idx & 3;
            *(short8_t*)&lA[row * 40 + cg * 8] = *(const short8_t*)&A[(size_t)(m0 + row) * 1024 + k0 + cg * 8];
            *(short8_t*)&lB[row * 40 + cg * 8] = *(const short8_t*)&Bm[(size_t)(n0 + row) * 1024 + k0 + cg * 8];
        }
        __syncthreads();
        short8_t af[4], bfr[4];
#pragma unroll
        for (int i = 0; i < 4; ++i) af[i] = *(short8_t*)&lA[(wm * 64 + i * 16 + lr) * 40 + lk];
#pragma unroll
        for (int j = 0; j < 4; ++j) bfr[j] = *(short8_t*)&lB[(wn * 64 + j * 16 + lr) * 40 + lk];
#pragma unroll
        for (int i = 0; i < 4; ++i)
#pragma unroll
            for (int j = 0; j < 4; ++j)
                acc[i][j] = __builtin_amdgcn_mfma_f32_16x16x32_bf16(af[i], bfr[j], acc[i][j], 0, 0, 0);
    }
    float cs[4] = {0.f, 0.f, 0.f, 0.f}, css[4] = {0.f, 0.f, 0.f, 0.f};
#pragma unroll
    for (int i = 0; i < 4; ++i) {
#pragma unroll
        for (int r = 0; r < 4; ++r) {
            int row = m0 + wm * 64 + i * 16 + g * 4 + r;
#pragma unroll
            for (int j = 0; j < 4; ++j) {
                float val = acc[i][j][r];
                cs[j] += val;
                css[j] += val * val;
                int col = n0 + wn * 64 + j * 16 + lr;
                Cout[(size_t)row * 256 + col] = val;
            }
        }
    }
    __syncthreads();
    float* red_s = (float*)lA;
    float* red_ss = (float*)lA + 1024;
#pragma unroll
    for (int j = 0; j < 4; ++j) {
        int c = wn * 64 + j * 16 + lr;
        red_s[(wm * 4 + g) * 128 + c] = cs[j];
        red_ss[(wm * 4 + g) * 128 + c] = css[j];
    }
    __syncthreads();
    if (tid < 128) {
        float s = 0.f;
#pragma unroll
        for (int u = 0; u < 8; ++u) s += red_s[u * 128 + tid];
        atomicAdd(&sum2[n0 + tid], s);
    } else {
        int c = tid - 128;
        float s = 0.f;
#pragma unroll
        for (int u = 0; u < 8; ++u) s += red_ss[u * 128 + c];
        atomicAdd(&sumsq2[n0 + c], s);
    }
}

__global__ void bn_finalize(const float* __restrict__ sum, const float* __restrict__ sumsq,
                            const float* __restrict__ g, const float* __restrict__ b,
                            float* __restrict__ scale, float* __restrict__ shift, int C, float invM) {
    int c = blockIdx.x * 256 + threadIdx.x;
    if (c < C) {
        float mean = sum[c] * invM;
        float var = sumsq[c] * invM - mean * mean;
        float sc = g[c] * rsqrtf(var + EPS);
        scale[c] = sc;
        shift[c] = b[c] - mean * sc;
    }
}

__global__ void prep_w(const float* __restrict__ scale1, const float* __restrict__ shift1,
                       float* __restrict__ wq, float* __restrict__ w2) {
    int c = threadIdx.x;
    if (c < 256) {
        int h = c >> 5, cc = c & 31;
        int qch = h * 192 + cc, kch = qch + 32;
        wq[c] = scale1[qch] * scale1[kch] * SCALE;
        w2[c] = shift1[qch] * scale1[kch] * SCALE;
    }
}

__global__ void uk_kernel(const unsigned short* __restrict__ qkB, const float* __restrict__ w2,
                          float* __restrict__ uk) {
    int idx = blockIdx.x * 256 + threadIdx.x;
    if (idx < 128 * 8 * 320) {
        int bh = idx / 320;
        int h = bh & 7;
        const unsigned short* kp = &qkB[(size_t)idx * 64 + 32];
        float s = 0.f;
#pragma unroll
        for (int c4 = 0; c4 < 4; ++c4) {
            short8_t kk = *(const short8_t*)&kp[c4 * 8];
#pragma unroll
            for (int j = 0; j < 8; ++j) s += bf2f((unsigned short)kk[j]) * w2[(h << 5) + c4 * 8 + j];
        }
        uk[idx] = s;
    }
}

__global__ void bias_build(const float* __restrict__ ab, const int* __restrict__ idxs,
                           unsigned short* __restrict__ biasb, int n_off) {
    int i = blockIdx.x * 256 + threadIdx.x;
    if (i < H_ * N_ * N_) {
        int h = i / (N_ * N_);
        int r = i % (N_ * N_);
        biasb[i] = f2bf(ab[h * n_off + idxs[r]]);
    }
}

// ---- attention v3: phase-split. block=(h, b*5+qt), 4 waves; wave=16 q-rows for QK/softmax,
// then wave=32 O-columns for PV (consuming all 4 waves' P slabs; V read once per block) ----
__global__ __launch_bounds__(256) void attn_kernel(const unsigned short* __restrict__ qkB,
                                                   const unsigned short* __restrict__ vT,
                                                   const float* __restrict__ wq,
                                                   const float* __restrict__ uk,
                                                   const unsigned short* __restrict__ biasb,
                                                   const float* __restrict__ scale1,
                                                   const float* __restrict__ shift1,
                                                   unsigned short* __restrict__ attnout) {
    __shared__ unsigned short Plds[4][10][16][40];  // [q-slab][k-32blk][row][32+8pad]
    __shared__ float sums[64];
    const int tid = threadIdx.x;
    const int lane = tid & 63, wid = tid >> 6;
    const int lr = lane & 15, g = lane >> 4;
    const int h = blockIdx.x;
    const int b = blockIdx.y / 5, qt = blockIdx.y % 5;
    const int bh = b * 8 + h;

    // Q fragment (wq = sq*sk*SCALE folded in)
    int qrow = qt * 64 + wid * 16 + lr;
    short8_t qraw = *(const short8_t*)&qkB[((size_t)bh * 320 + qrow) * 64 + g * 8];
    short8_t aq;
#pragma unroll
    for (int j = 0; j < 8; ++j)
        aq[j] = (short)f2bf(bf2f((unsigned short)qraw[j]) * wq[(h << 5) + g * 8 + j]);

    // ---- phase 1: all QK^T MFMAs (independent K loads) ----
    const unsigned short* Kbase = &qkB[(size_t)bh * 320 * 64 + 32 + g * 8];
    f32x4 sacc[20];
#pragma unroll
    for (int t = 0; t < 20; ++t) {
        short8_t bk = *(const short8_t*)&Kbase[(size_t)(t * 16 + lr) * 64];
        f32x4 z = {};
        sacc[t] = __builtin_amdgcn_mfma_f32_16x16x32_bf16(aq, bk, z, 0, 0, 0);
    }

    // ---- phase 2: bias + exp + pack P into this wave's LDS slab ----
    const int nloc0 = qt * 64 + wid * 16 + g * 4;
    const unsigned short* biasrow = &biasb[(size_t)h * 320 * 320];
    const float* ukrow = &uk[(size_t)bh * 320];
    float sumr[4] = {0.f, 0.f, 0.f, 0.f};
#pragma unroll
    for (int t = 0; t < 20; ++t) {
        float ukv = ukrow[t * 16 + lr];
#pragma unroll
        for (int r = 0; r < 4; ++r) {
            float s = sacc[t][r] + ukv + bf2f(biasrow[(size_t)(nloc0 + r) * 320 + t * 16 + lr]);
            float p = __expf(s);
            sumr[r] += p;
            Plds[wid][t >> 1][g * 4 + r][(t & 1) * 16 + lr] = f2bf(p);
        }
    }
#pragma unroll
    for (int r = 0; r < 4; ++r) {
#pragma unroll
        for (int ms = 1; ms < 16; ms <<= 1) sumr[r] += __shfl_xor(sumr[r], ms);
        if (lr == 0) sums[wid * 16 + g * 4 + r] = sumr[r];
    }
    __syncthreads();

    // ---- phase 3: PV. wave wid owns O-cols [wid*32, wid*32+32); V read once per block ----
    const unsigned short* Vb = &vT[(size_t)bh * 128 * 320 + g * 8];
    f32x4 oacc[4][2] = {};
#pragma unroll
    for (int t = 0; t < 10; ++t) {
        short8_t bv0 = *(const short8_t*)&Vb[(size_t)(wid * 32 + lr) * 320 + t * 32];
        short8_t bv1 = *(const short8_t*)&Vb[(size_t)(wid * 32 + 16 + lr) * 320 + t * 32];
#pragma unroll
        for (int qw = 0; qw < 4; ++qw) {
            short8_t ap = *(short8_t*)&Plds[qw][t][lr][g * 8];
            oacc[qw][0] = __builtin_amdgcn_mfma_f32_16x16x32_bf16(ap, bv0, oacc[qw][0], 0, 0, 0);
            oacc[qw][1] = __builtin_amdgcn_mfma_f32_16x16x32_bf16(ap, bv1, oacc[qw][1], 0, 0, 0);
        }
    }

    // ---- epilogue: normalize, fold V-BN, GELU ----
    float svv[2], tvv[2];
#pragma unroll
    for (int dtl = 0; dtl < 2; ++dtl) {
        int ch = h * 192 + 64 + wid * 32 + dtl * 16 + lr;
        svv[dtl] = scale1[ch];
        tvv[dtl] = shift1[ch];
    }
#pragma unroll
    for (int qw = 0; qw < 4; ++qw) {
#pragma unroll
        for (int r = 0; r < 4; ++r) {
            float inv = 1.0f / sums[qw * 16 + g * 4 + r];
            size_t nrow = (size_t)b * 320 + qt * 64 + qw * 16 + g * 4 + r;
#pragma unroll
            for (int dtl = 0; dtl < 2; ++dtl) {
                float v = oacc[qw][dtl][r] * inv * svv[dtl] + tvv[dtl];
                float ge = 0.5f * v * (1.0f + erff(v * 0.70710678118f));
                attnout[nrow * 1024 + h * 128 + wid * 32 + dtl * 16 + lr] = f2bf(ge);
            }
        }
    }
}

__global__ void bn_apply(float* __restrict__ out, const float* __restrict__ scale,
                         const float* __restrict__ shift) {
    int i = blockIdx.x * 256 + threadIdx.x;
    const int total = MROWS * C_ / 4;
    for (; i < total; i += gridDim.x * 256) {
        f32x4 v = *(const f32x4*)&out[(size_t)i * 4];
        int c = (i * 4) & 255;
        f32x4 o;
#pragma unroll
        for (int j = 0; j < 4; ++j) o[j] = v[j] * scale[c + j] + shift[c + j];
        *(f32x4*)&out[(size_t)i * 4] = o;
    }
}

extern "C" void kernel_launch(void* const* d_in, const int* in_sizes, int n_in,
                              void* d_out, int out_size, void* d_ws, size_t ws_size,
                              hipStream_t stream) {
    const float* x = (const float*)d_in[0];
    const float* Wqkv = (const float*)d_in[1];
    const float* g1 = (const float*)d_in[2];
    const float* b1 = (const float*)d_in[3];
    const float* ab = (const float*)d_in[4];
    const float* Wproj = (const float*)d_in[5];
    const float* g2 = (const float*)d_in[6];
    const float* b2 = (const float*)d_in[7];
    const int* idxs = (const int*)d_in[8];
    const int n_off = in_sizes[4] / H_;

    char* ws = (char*)d_ws;
    unsigned short* qkB = (unsigned short*)ws;                       // 41.9MB
    unsigned short* vT = (unsigned short*)(ws + 41943040);           // 83.9MB
    unsigned short* attnout = (unsigned short*)(ws + 125829120);     // 83.9MB
    unsigned short* xb = attnout;                                    // overlap: dead before attn
    unsigned short* biasb = (unsigned short*)(ws + 209715200);       // 1.64MB bf16
    float* uk = (float*)(ws + 212992000);                            // 1.31MB
    unsigned short* wqb = (unsigned short*)(ws + 214302720);
    unsigned short* wpb = (unsigned short*)(ws + 215089152);
    float* stats = (float*)(ws + 215613440);
    float* sum1 = stats;
    float* sumsq1 = stats + 1536;
    float* sum2 = stats + 3072;
    float* sumsq2 = sum2 + 256;
    float* scale1 = sumsq2 + 256;
    float* shift1 = scale1 + 1536;
    float* scale2 = shift1 + 1536;
    float* shift2 = scale2 + 256;
    float* wq = shift2 + 256;
    float* w2 = wq + 256;

    hipMemsetAsync(stats, 0, 3584 * 4, stream);
    conv_bf16<<<dim3(10240), 256, 0, stream>>>(x, xb, 2621440);
    conv_bf16<<<dim3(384), 256, 0, stream>>>(Wqkv, wqb, 98304);
    conv_bf16<<<dim3(256), 256, 0, stream>>>(Wproj, wpb, 65536);
    bias_build<<<dim3(3200), 256, 0, stream>>>(ab, idxs, biasb, n_off);
    gemm_qkv<<<dim3(12, 320), 256, 0, stream>>>(xb, wqb, qkB, vT, sum1, sumsq1);
    bn_finalize<<<dim3(6), 256, 0, stream>>>(sum1, sumsq1, g1, b1, scale1, shift1, 1536, 1.0f / MROWS);
    prep_w<<<dim3(1), 256, 0, stream>>>(scale1, shift1, wq, w2);
    uk_kernel<<<dim3(1280), 256, 0, stream>>>(qkB, w2, uk);
    attn_kernel<<<dim3(8, 640), 256, 0, stream>>>(qkB, vT, wq, uk, biasb, scale1, shift1, attnout);
    gemm_proj<<<dim3(2, 320), 256, 0, stream>>>(attnout, wpb, (float*)d_out, sum2, sumsq2);
    bn_finalize<<<dim3(1), 256, 0, stream>>>(sum2, sumsq2, g2, b2, scale2, shift2, 256, 1.0f / MROWS);
    bn_apply<<<dim3(2048), 256, 0, stream>>>((float*)d_out, scale2, shift2);
}